// Round 8
// baseline (177.446 us; speedup 1.0000x reference)
//
#include <hip/hip_runtime.h>

// 2-level 2D Haar DWT, fused, one 4x8 input patch per thread.
// x: (96, 512, 512) fp32.
// History (all ~60us / 2.5 TB/s HBM-side): persistent depth-1 prefetch ==
// full-grid 58%-occ == NT stores == 4x8 reg patch == 32KB/block async
// global_load_lds staging. Round 5 falsified per-wave read depth (160KB/CU in
// flight, ~3KB needed). Rounds 6/7: container failed twice on the variant
// adding __builtin_nontemporal_load -- that builtin is quarantined; this round
// tests ONLY the XCD-bijective chunked swizzle, using proven constructs.
//   Default dispatch round-robins consecutive blockIdx across 8 XCDs -> each
//   XCD's L2 fetches interleaved shreds of all 96 images. Chunked remap
//   (lbid = (bid%8)*(nwg/8) + bid/8, bijective since nwg%8==0) gives each XCD
//   a contiguous 12-image slab: L2-local fetch, sequential DRAM pages.
// Stores: round-2-proven shapes (v4f/v2f lane-contiguous, NT, WRITE_SIZE 1x).
// Per-element arithmetic identical to reference (W first, then H, *KINV each
// stage). Out layout: a2,h2,v2,d2 (96*128*128 each), h1,v1,d1 (96*256*256 each).

#define KINV 0.7071067811865476f

typedef float v4f __attribute__((ext_vector_type(4)));
typedef float v2f __attribute__((ext_vector_type(2)));

#define NXCD 8

__global__ __launch_bounds__(256, 4) void haar2_fused_kernel(
    const float* __restrict__ x, float* __restrict__ out, int nimg)
{
    // XCD-bijective chunked swizzle (gridDim.x % 8 == 0 by construction).
    const int nwg = (int)gridDim.x;
    const int cpx = nwg / NXCD;
    const int bid = (int)blockIdx.x;
    const int lbid = (bid % NXCD) * cpx + (bid / NXCD);

    const int tid = lbid * (int)blockDim.x + (int)threadIdx.x; // 0..nimg*8192-1
    const int cx  = tid & 63;           // 8-col patch index (lane-fast)
    const int r2  = (tid >> 6) & 127;   // level-2 row
    const int img = tid >> 13;          // 0..95

    const int row0 = r2 * 4;
    const int col0 = cx * 8;

    const size_t n2 = (size_t)nimg * 128 * 128;
    const size_t n1 = (size_t)nimg * 256 * 256;
    float* a2o = out;
    float* h2o = out + n2;
    float* v2o = out + 2 * n2;
    float* d2o = out + 3 * n2;
    float* h1o = out + 4 * n2;
    float* v1o = h1o + n1;
    float* d1o = h1o + 2 * n1;

    // 8 x 16B cached loads (plain — the NT-load builtin is quarantined after
    // two container failures).
    const size_t in_base = (size_t)img * (512 * 512) + (size_t)row0 * 512 + col0;
    v4f bA[4], bB[4];
    #pragma unroll
    for (int k = 0; k < 4; ++k) {
        bA[k] = *reinterpret_cast<const v4f*>(x + in_base + (size_t)k * 512);
        bB[k] = *reinterpret_cast<const v4f*>(x + in_base + (size_t)k * 512 + 4);
    }

    // ---- Level 1 (W-axis first, then H-axis, *KINV each stage).
    float aaL[2][2], daL[2][2], adL[2][2], ddL[2][2];
    float aaR[2][2], daR[2][2], adR[2][2], ddR[2][2];
    #pragma unroll
    for (int i = 0; i < 2; ++i) {
        {
            const v4f top = bA[2 * i], bot = bA[2 * i + 1];
            const float sA0 = (top.x + top.y) * KINV, dA0 = (top.x - top.y) * KINV;
            const float sB0 = (bot.x + bot.y) * KINV, dB0 = (bot.x - bot.y) * KINV;
            aaL[i][0] = (sA0 + sB0) * KINV; daL[i][0] = (sA0 - sB0) * KINV;
            adL[i][0] = (dA0 + dB0) * KINV; ddL[i][0] = (dA0 - dB0) * KINV;
            const float sA1 = (top.z + top.w) * KINV, dA1 = (top.z - top.w) * KINV;
            const float sB1 = (bot.z + bot.w) * KINV, dB1 = (bot.z - bot.w) * KINV;
            aaL[i][1] = (sA1 + sB1) * KINV; daL[i][1] = (sA1 - sB1) * KINV;
            adL[i][1] = (dA1 + dB1) * KINV; ddL[i][1] = (dA1 - dB1) * KINV;
        }
        {
            const v4f top = bB[2 * i], bot = bB[2 * i + 1];
            const float sA0 = (top.x + top.y) * KINV, dA0 = (top.x - top.y) * KINV;
            const float sB0 = (bot.x + bot.y) * KINV, dB0 = (bot.x - bot.y) * KINV;
            aaR[i][0] = (sA0 + sB0) * KINV; daR[i][0] = (sA0 - sB0) * KINV;
            adR[i][0] = (dA0 + dB0) * KINV; ddR[i][0] = (dA0 - dB0) * KINV;
            const float sA1 = (top.z + top.w) * KINV, dA1 = (top.z - top.w) * KINV;
            const float sB1 = (bot.z + bot.w) * KINV, dB1 = (bot.z - bot.w) * KINV;
            aaR[i][1] = (sA1 + sB1) * KINV; daR[i][1] = (sA1 - sB1) * KINV;
            adR[i][1] = (dA1 + dB1) * KINV; ddR[i][1] = (dA1 - dB1) * KINV;
        }
    }

    // ---- Level-1 detail stores: v4f, lanes at 16B stride -> contiguous 1KB
    // per instruction per wave. NT stores (proven). WRITE_SIZE verified 1x.
    const size_t img1 = (size_t)img * 256 * 256;
    #pragma unroll
    for (int i = 0; i < 2; ++i) {
        const size_t off = img1 + (size_t)(2 * r2 + i) * 256 + (size_t)cx * 4;
        __builtin_nontemporal_store((v4f){daL[i][0], daL[i][1], daR[i][0], daR[i][1]},
                                    reinterpret_cast<v4f*>(h1o + off));
        __builtin_nontemporal_store((v4f){adL[i][0], adL[i][1], adR[i][0], adR[i][1]},
                                    reinterpret_cast<v4f*>(v1o + off));
        __builtin_nontemporal_store((v4f){ddL[i][0], ddL[i][1], ddR[i][0], ddR[i][1]},
                                    reinterpret_cast<v4f*>(d1o + off));
    }

    // ---- Level 2 (L -> col 2cx, R -> col 2cx+1); v2f lane-contiguous. NT.
    const float s0L = (aaL[0][0] + aaL[0][1]) * KINV;
    const float d0L = (aaL[0][0] - aaL[0][1]) * KINV;
    const float s1L = (aaL[1][0] + aaL[1][1]) * KINV;
    const float d1L = (aaL[1][0] - aaL[1][1]) * KINV;
    const float s0R = (aaR[0][0] + aaR[0][1]) * KINV;
    const float d0R = (aaR[0][0] - aaR[0][1]) * KINV;
    const float s1R = (aaR[1][0] + aaR[1][1]) * KINV;
    const float d1R = (aaR[1][0] - aaR[1][1]) * KINV;

    const size_t off2 = (size_t)img * 128 * 128 + (size_t)r2 * 128 + 2 * cx;
    __builtin_nontemporal_store((v2f){(s0L + s1L) * KINV, (s0R + s1R) * KINV},
                                reinterpret_cast<v2f*>(a2o + off2));
    __builtin_nontemporal_store((v2f){(s0L - s1L) * KINV, (s0R - s1R) * KINV},
                                reinterpret_cast<v2f*>(h2o + off2));
    __builtin_nontemporal_store((v2f){(d0L + d1L) * KINV, (d0R + d1R) * KINV},
                                reinterpret_cast<v2f*>(v2o + off2));
    __builtin_nontemporal_store((v2f){(d0L - d1L) * KINV, (d0R - d1R) * KINV},
                                reinterpret_cast<v2f*>(d2o + off2));
}

extern "C" void kernel_launch(void* const* d_in, const int* in_sizes, int n_in,
                              void* d_out, int out_size, void* d_ws, size_t ws_size,
                              hipStream_t stream) {
    const float* x = (const float*)d_in[0];
    float* out = (float*)d_out;
    const int nimg = in_sizes[0] / (512 * 512);   // 96
    const int total_threads = nimg * 128 * 64;    // 786,432 threads (4x8 patch)
    const int block = 256;
    const int grid = total_threads / block;       // 3072 blocks (384/XCD chunks)
    haar2_fused_kernel<<<grid, block, 0, stream>>>(x, out, nimg);
}